// Round 1
// baseline (1131.852 us; speedup 1.0000x reference)
//
#include <hip/hip_runtime.h>
#include <hip/hip_bf16.h>

#define B_   4
#define M_   8192
#define N_   32768
#define H_   128
#define EPS_ 1e-5f
#define TBL  1048576   // 4 * 64^3 dense hash table

// ---------------------------------------------------------------- prep
// pack xyz (5 bits each), compute hash key, scatter into dense table
__global__ __launch_bounds__(256) void prep_kernel(const int* __restrict__ coords,
                                                   int* __restrict__ table,
                                                   int* __restrict__ packed,
                                                   int* __restrict__ keyb) {
    int n = blockIdx.x * 256 + threadIdx.x;
    int b = coords[4*n+0], x = coords[4*n+1], y = coords[4*n+2], z = coords[4*n+3];
    packed[n] = (x << 10) | (y << 5) | z;
    int key = ((b*64 + x+1)*64 + y+1)*64 + (z+1);
    keyb[n] = key;
    table[key] = n;
}

// ---------------------------------------------------------------- kNN
// 64 queries/block, 2-way split scan over 8192 candidates, merge top-8.
// key = (d2<<13)|j  == (d2, idx) lexicographic == jax.lax.top_k stable order
__global__ __launch_bounds__(128) void knn_kernel(const int* __restrict__ packed,
                                                  int* __restrict__ nbr) {
    __shared__ int cand[M_];         // 32 KB: whole batch, packed coords
    __shared__ int tops[128][8];
    int tid = threadIdx.x;
    int qbase = blockIdx.x * 64;
    int batch = qbase / M_;
    int bb = batch * M_;

    const int4* src = (const int4*)(packed + bb);
    int4* dst = (int4*)cand;
    for (int i = tid; i < M_/4; i += 128) dst[i] = src[i];
    __syncthreads();

    int t64 = tid & 63;
    int half = tid >> 6;
    int row = qbase + t64;
    int lq = row - bb;
    int p = cand[lq];
    int qx = (p >> 10) & 31, qy = (p >> 5) & 31, qz = p & 31;

    int top[8];
#pragma unroll
    for (int k = 0; k < 8; ++k) top[k] = 0x7FFFFFFF;

    int j0 = half * (M_/2), j1 = j0 + (M_/2);
    for (int j = j0; j < j1; ++j) {
        int c = cand[j];
        int dx = qx - ((c >> 10) & 31);
        int dy = qy - ((c >> 5) & 31);
        int dz = qz - (c & 31);
        int d2 = dx*dx + dy*dy + dz*dz;
        int key = (d2 << 13) | j;
        if (key < top[7]) {
#pragma unroll
            for (int k = 7; k >= 1; --k)
                top[k] = (key < top[k]) ? max(key, top[k-1]) : top[k];
            top[0] = min(key, top[0]);
        }
    }
#pragma unroll
    for (int k = 0; k < 8; ++k) tops[tid][k] = top[k];
    __syncthreads();

    if (tid < 64) {
        const int* A  = tops[tid];
        const int* Bt = tops[tid + 64];
        int ia = 0, ib = 0;
        int* outp = nbr + row * 8;
#pragma unroll
        for (int k = 0; k < 8; ++k) {
            int a = A[ia], b2 = Bt[ib];
            int v;
            if (a <= b2) { v = a; ++ia; } else { v = b2; ++ib; }
            outp[k] = bb + (v & 8191);
        }
    }
}

// ---------------------------------------------------------------- 1x1 conv (combined @ w1)
// 16 rows/block; LDS holds gathered combined [16][72]
__global__ __launch_bounds__(256) void h1_kernel(const float* __restrict__ feats,
                                                 const int* __restrict__ nbr,
                                                 const float* __restrict__ w1,
                                                 float* __restrict__ hpre) {
    __shared__ float comb[16][72];
    int tid = threadIdx.x;
    int rowbase = blockIdx.x * 16;
    if (tid < 144) {
        int r = tid / 9, s = tid % 9;
        int grow = rowbase + r;
        int idx = (s == 0) ? grow : nbr[grow*8 + (s-1)];
        const float4* f = (const float4*)(feats + idx * 8);
        float4 a = f[0], b = f[1];
        float* dp = &comb[r][s*8];
        dp[0]=a.x; dp[1]=a.y; dp[2]=a.z; dp[3]=a.w;
        dp[4]=b.x; dp[5]=b.y; dp[6]=b.z; dp[7]=b.w;
    }
    __syncthreads();
    int c = tid & 127, rh = tid >> 7;
    float acc[8];
#pragma unroll
    for (int i = 0; i < 8; ++i) acc[i] = 0.f;
    for (int s = 0; s < 72; ++s) {
        float w = w1[s*128 + c];
#pragma unroll
        for (int i = 0; i < 8; ++i)
            acc[i] += comb[rh*8 + i][s] * w;
    }
#pragma unroll
    for (int i = 0; i < 8; ++i)
        hpre[(rowbase + rh*8 + i)*128 + c] = acc[i];
}

// ---------------------------------------------------------------- BN stats: two-level deterministic reduce
__global__ __launch_bounds__(256) void reduce_kernel(const float* __restrict__ src,
                                                     float* __restrict__ part) {
    __shared__ float ssum[256], ssq[256];
    int tid = threadIdx.x;
    int c = tid & 127, halfr = tid >> 7;
    int rowbase = blockIdx.x * 128 + halfr * 64;
    float s = 0.f, q = 0.f;
    for (int i = 0; i < 64; ++i) {
        float v = src[(rowbase + i)*128 + c];
        s += v; q += v*v;
    }
    ssum[tid] = s; ssq[tid] = q;
    __syncthreads();
    if (tid < 128) {
        part[blockIdx.x*256 + tid]       = ssum[tid] + ssum[tid+128];
        part[blockIdx.x*256 + 128 + tid] = ssq[tid]  + ssq[tid+128];
    }
}

__global__ __launch_bounds__(128) void stats_kernel(const float* __restrict__ part,
                                                    const float* __restrict__ g,
                                                    const float* __restrict__ bias,
                                                    float* __restrict__ scale,
                                                    float* __restrict__ shift) {
    int c = threadIdx.x;
    float s = 0.f, q = 0.f;
    for (int b = 0; b < 256; ++b) {
        s += part[b*256 + c];
        q += part[b*256 + 128 + c];
    }
    float mu  = s / (float)N_;
    float var = q / (float)N_ - mu*mu;
    float inv = rsqrtf(var + EPS_);
    float sc  = inv * g[c];
    scale[c] = sc;
    shift[c] = bias[c] - mu * sc;
}

__global__ __launch_bounds__(256) void bnrelu_kernel(float* __restrict__ x,
                                                     const float* __restrict__ scale,
                                                     const float* __restrict__ shift) {
    int i = blockIdx.x * 256 + threadIdx.x;      // float4 index; grid covers N*128/4
    float4 v = ((const float4*)x)[i];
    int c = (i * 4) & 127;
    v.x = fmaxf(0.f, v.x*scale[c]   + shift[c]);
    v.y = fmaxf(0.f, v.y*scale[c+1] + shift[c+1]);
    v.z = fmaxf(0.f, v.z*scale[c+2] + shift[c+2]);
    v.w = fmaxf(0.f, v.w*scale[c+3] + shift[c+3]);
    ((float4*)x)[i] = v;
}

// ---------------------------------------------------------------- 3^3 sparse conv (gather-GEMM, fp32)
// 32 rows/block; per offset o: gather h rows -> LDS transposed [c][row];
// each thread: 4 rows x 4 out-cols register tile.
#define CSTRIDE 36   // pad 32->36 keeps float4 alignment, breaks pow2 bank stride
__global__ __launch_bounds__(256) void conv3_kernel(const float* __restrict__ h,
                                                    const float* __restrict__ w3,
                                                    const int* __restrict__ table,
                                                    const int* __restrict__ keyb,
                                                    float* __restrict__ h2) {
    __shared__ __align__(16) float At[128 * CSTRIDE];  // [c][row]
    __shared__ int jsh[32];
    int tid = threadIdx.x;
    int rowbase = blockIdx.x * 32;
    int rg = tid >> 5, dg = tid & 31;
    float acc[4][4];
#pragma unroll
    for (int i = 0; i < 4; ++i)
#pragma unroll
        for (int k = 0; k < 4; ++k) acc[i][k] = 0.f;

    for (int o = 0; o < 27; ++o) {
        int dx = o/9 - 1, dy = (o/3)%3 - 1, dz = o%3 - 1;
        int okey = dx*4096 + dy*64 + dz;
        __syncthreads();                       // protect At/jsh from previous iter
        if (tid < 32) jsh[tid] = table[keyb[rowbase + tid] + okey];
        __syncthreads();
#pragma unroll
        for (int t = 0; t < 16; ++t) {
            int flat = t*256 + tid;
            int r = flat >> 7, c = flat & 127;
            int j = jsh[r];
            At[c*CSTRIDE + r] = (j >= 0) ? h[j*128 + c] : 0.f;
        }
        __syncthreads();
        const float* w3o = w3 + o*128*128;
#pragma unroll 4
        for (int c = 0; c < 128; ++c) {
            float4 a = *(const float4*)&At[c*CSTRIDE + 4*rg];
            float4 w = *(const float4*)&w3o[c*128 + 4*dg];
            acc[0][0] += a.x*w.x; acc[0][1] += a.x*w.y; acc[0][2] += a.x*w.z; acc[0][3] += a.x*w.w;
            acc[1][0] += a.y*w.x; acc[1][1] += a.y*w.y; acc[1][2] += a.y*w.z; acc[1][3] += a.y*w.w;
            acc[2][0] += a.z*w.x; acc[2][1] += a.z*w.y; acc[2][2] += a.z*w.z; acc[2][3] += a.z*w.w;
            acc[3][0] += a.w*w.x; acc[3][1] += a.w*w.y; acc[3][2] += a.w*w.z; acc[3][3] += a.w*w.w;
        }
    }
#pragma unroll
    for (int i = 0; i < 4; ++i) {
        float4 v = make_float4(acc[i][0], acc[i][1], acc[i][2], acc[i][3]);
        *(float4*)&h2[(rowbase + 4*rg + i)*128 + 4*dg] = v;
    }
}

// ---------------------------------------------------------------- final 1x1 conv
__global__ __launch_bounds__(256) void out_kernel(const float* __restrict__ h2,
                                                  const float* __restrict__ wout,
                                                  float* __restrict__ out) {
    int tid = threadIdx.x;
    int r = tid >> 4, d = tid & 15;
    int row = blockIdx.x * 16 + r;
    float acc = 0.f;
    for (int c = 0; c < 128; ++c)
        acc += h2[row*128 + c] * wout[c*16 + d];
    out[row*16 + d] = acc;
}

// ---------------------------------------------------------------- launch
extern "C" void kernel_launch(void* const* d_in, const int* in_sizes, int n_in,
                              void* d_out, int out_size, void* d_ws, size_t ws_size,
                              hipStream_t stream) {
    const int*   coords = (const int*)d_in[0];
    const float* feats  = (const float*)d_in[1];
    const float* w1     = (const float*)d_in[2];
    const float* g1     = (const float*)d_in[3];
    const float* b1     = (const float*)d_in[4];
    const float* w3     = (const float*)d_in[5];
    const float* g2     = (const float*)d_in[6];
    const float* b2     = (const float*)d_in[7];
    const float* wout   = (const float*)d_in[8];
    float* out = (float*)d_out;

    char* ws = (char*)d_ws;
    int*   table  = (int*)(ws);                               // 4 MB
    int*   packed = (int*)(ws + (4u<<20));                    // 128 KB
    int*   keyb   = (int*)(ws + (4u<<20) + (256u<<10));       // 128 KB
    int*   nbr    = (int*)(ws + (5u<<20));                    // 1 MB
    float* h      = (float*)(ws + (6u<<20));                  // 16 MB
    float* h2     = (float*)(ws + (22u<<20));                 // 16 MB
    float* part   = (float*)(ws + (38u<<20));                 // 256 KB
    float* scale1 = (float*)(ws + (39u<<20));
    float* shift1 = scale1 + 128;
    float* scale2 = shift1 + 128;
    float* shift2 = scale2 + 128;

    hipMemsetAsync(table, 0xFF, TBL * sizeof(int), stream);   // table = -1
    prep_kernel  <<<N_/256, 256, 0, stream>>>(coords, table, packed, keyb);
    knn_kernel   <<<N_/64, 128, 0, stream>>>(packed, nbr);
    h1_kernel    <<<N_/16, 256, 0, stream>>>(feats, nbr, w1, h);
    reduce_kernel<<<N_/128, 256, 0, stream>>>(h, part);
    stats_kernel <<<1, 128, 0, stream>>>(part, g1, b1, scale1, shift1);
    bnrelu_kernel<<<(N_*H_/4)/256, 256, 0, stream>>>(h, scale1, shift1);
    conv3_kernel <<<N_/32, 256, 0, stream>>>(h, w3, table, keyb, h2);
    reduce_kernel<<<N_/128, 256, 0, stream>>>(h2, part);
    stats_kernel <<<1, 128, 0, stream>>>(part, g2, b2, scale2, shift2);
    bnrelu_kernel<<<(N_*H_/4)/256, 256, 0, stream>>>(h2, scale2, shift2);
    out_kernel   <<<N_/16, 256, 0, stream>>>(h2, wout, out);
}

// Round 2
// 644.852 us; speedup vs baseline: 1.7552x; 1.7552x over previous
//
#include <hip/hip_runtime.h>
#include <hip/hip_bf16.h>

#define B_   4
#define M_   8192
#define N_   32768
#define H_   128
#define EPS_ 1e-5f
#define TBL  1048576   // 4 * 64^3 dense hash table
#define GUARD 8192     // negative-offset guard for window probes

// ---------------------------------------------------------------- prep
__global__ __launch_bounds__(256) void prep_kernel(const int* __restrict__ coords,
                                                   int* __restrict__ table,
                                                   int* __restrict__ packed,
                                                   int* __restrict__ keyb) {
    int n = blockIdx.x * 256 + threadIdx.x;
    int b = coords[4*n+0], x = coords[4*n+1], y = coords[4*n+2], z = coords[4*n+3];
    packed[n] = (x << 10) | (y << 5) | z;
    int key = ((b*64 + x+1)*64 + y+1)*64 + (z+1);
    keyb[n] = key;
    table[key] = n;
}

// ---------------------------------------------------------------- kNN via radius-2 window on the dense voxel table
// Exact iff 8th-best d2 <= 8 (outside box => d2 >= 9); else flag for brute force.
// key = (d2<<13)|j  == (d2, idx) lexicographic == jax.lax.top_k stable order.
__global__ __launch_bounds__(256) void knn_window_kernel(const int* __restrict__ table,
                                                         const int* __restrict__ keyb,
                                                         int* __restrict__ nbr,
                                                         int* __restrict__ flagcnt,
                                                         int* __restrict__ flaglist) {
    __shared__ int okey_sh[125], d2_sh[125];
    __shared__ int tops[256 * 8];
    int tid = threadIdx.x;
    if (tid < 125) {
        int dx = tid / 25 - 2, rr = tid % 25, dy = rr / 5 - 2, dz = rr % 5 - 2;
        okey_sh[tid] = dx * 4096 + dy * 64 + dz;
        d2_sh[tid]   = dx*dx + dy*dy + dz*dz;
    }
    __syncthreads();

    int q   = blockIdx.x * 64 + (tid >> 2);
    int sub = tid & 3;
    int kb  = keyb[q];

    int top[8];
#pragma unroll
    for (int k = 0; k < 8; ++k) top[k] = 0x7FFFFFFF;

    int base = sub * 32;
    int cnt  = (sub == 3) ? 29 : 32;          // 125 probes split 32/32/32/29
    for (int i = 0; i < cnt; ++i) {
        int idx = base + i;
        int j = table[kb + okey_sh[idx]];
        if (j >= 0) {
            int key = (d2_sh[idx] << 13) | (j & 8191);
            if (key < top[7]) {
#pragma unroll
                for (int k = 7; k >= 1; --k)
                    top[k] = (key < top[k]) ? max(key, top[k-1]) : top[k];
                top[0] = min(key, top[0]);
            }
        }
    }
#pragma unroll
    for (int k = 0; k < 8; ++k) tops[tid*8 + k] = top[k];
    __syncthreads();

    if (sub == 0) {
        // serial 4-way merge of sorted 8-lists
        const int* L = &tops[tid*8];
        int ia0 = 0, ia1 = 0, ia2 = 0, ia3 = 0;
        int res[8];
#pragma unroll
        for (int k = 0; k < 8; ++k) {
            int v0 = L[ia0], v1 = L[8 + ia1], v2 = L[16 + ia2], v3 = L[24 + ia3];
            int m01 = min(v0, v1), m23 = min(v2, v3);
            int m = min(m01, m23);
            res[k] = m;
            if (m == v0) ++ia0; else if (m == v1) ++ia1;
            else if (m == v2) ++ia2; else ++ia3;
        }
        int bb = q & ~(M_-1);
        if ((res[7] >> 13) <= 8) {
#pragma unroll
            for (int k = 0; k < 8; ++k) nbr[q*8 + k] = bb + (res[k] & 8191);
        } else {
            int pos = atomicAdd(flagcnt, 1);
            flaglist[pos] = q;
        }
    }
}

// ---------------------------------------------------------------- exact brute-force cleanup for flagged queries
__global__ __launch_bounds__(256) void knn_bf_kernel(const int* __restrict__ packed,
                                                     const int* __restrict__ flagcnt,
                                                     const int* __restrict__ flaglist,
                                                     int* __restrict__ nbr) {
    __shared__ int tops[256 * 8];
    int tid = threadIdx.x;
    int cnt = *flagcnt;
    for (int f = blockIdx.x; f < cnt; f += gridDim.x) {
        int n = flaglist[f];
        int bb = n & ~(M_-1);
        int p = packed[n];
        int qx = (p >> 10) & 31, qy = (p >> 5) & 31, qz = p & 31;
        int top[8];
#pragma unroll
        for (int k = 0; k < 8; ++k) top[k] = 0x7FFFFFFF;
        for (int j = tid; j < M_; j += 256) {
            int c = packed[bb + j];
            int dx = qx - ((c >> 10) & 31);
            int dy = qy - ((c >> 5) & 31);
            int dz = qz - (c & 31);
            int d2 = dx*dx + dy*dy + dz*dz;
            int key = (d2 << 13) | j;
            if (key < top[7]) {
#pragma unroll
                for (int k = 7; k >= 1; --k)
                    top[k] = (key < top[k]) ? max(key, top[k-1]) : top[k];
                top[0] = min(key, top[0]);
            }
        }
#pragma unroll
        for (int k = 0; k < 8; ++k) tops[tid*8 + k] = top[k];
        __syncthreads();
        for (int stride = 128; stride >= 1; stride >>= 1) {
            if (tid < stride) {
                int* A  = &tops[tid*8];
                int* Bp = &tops[(tid+stride)*8];
                int r[8]; int ia = 0, ib = 0;
#pragma unroll
                for (int k = 0; k < 8; ++k) {
                    int a = A[ia], b2 = Bp[ib];
                    if (a <= b2) { r[k] = a; ++ia; } else { r[k] = b2; ++ib; }
                }
#pragma unroll
                for (int k = 0; k < 8; ++k) A[k] = r[k];
            }
            __syncthreads();
        }
        if (tid == 0) {
#pragma unroll
            for (int k = 0; k < 8; ++k) nbr[n*8 + k] = bb + (tops[k] & 8191);
        }
        __syncthreads();
    }
}

// ---------------------------------------------------------------- 1x1 conv (combined @ w1)
__global__ __launch_bounds__(256) void h1_kernel(const float* __restrict__ feats,
                                                 const int* __restrict__ nbr,
                                                 const float* __restrict__ w1,
                                                 float* __restrict__ hpre) {
    __shared__ float comb[16][72];
    int tid = threadIdx.x;
    int rowbase = blockIdx.x * 16;
    if (tid < 144) {
        int r = tid / 9, s = tid % 9;
        int grow = rowbase + r;
        int idx = (s == 0) ? grow : nbr[grow*8 + (s-1)];
        const float4* f = (const float4*)(feats + idx * 8);
        float4 a = f[0], b = f[1];
        float* dp = &comb[r][s*8];
        dp[0]=a.x; dp[1]=a.y; dp[2]=a.z; dp[3]=a.w;
        dp[4]=b.x; dp[5]=b.y; dp[6]=b.z; dp[7]=b.w;
    }
    __syncthreads();
    int c = tid & 127, rh = tid >> 7;
    float acc[8];
#pragma unroll
    for (int i = 0; i < 8; ++i) acc[i] = 0.f;
    for (int s = 0; s < 72; ++s) {
        float w = w1[s*128 + c];
#pragma unroll
        for (int i = 0; i < 8; ++i)
            acc[i] += comb[rh*8 + i][s] * w;
    }
#pragma unroll
    for (int i = 0; i < 8; ++i)
        hpre[(rowbase + rh*8 + i)*128 + c] = acc[i];
}

// ---------------------------------------------------------------- BN stats
__global__ __launch_bounds__(256) void reduce_kernel(const float* __restrict__ src,
                                                     float* __restrict__ part) {
    __shared__ float ssum[256], ssq[256];
    int tid = threadIdx.x;
    int c = tid & 127, halfr = tid >> 7;
    int rowbase = blockIdx.x * 128 + halfr * 64;
    float s = 0.f, q = 0.f;
    for (int i = 0; i < 64; ++i) {
        float v = src[(rowbase + i)*128 + c];
        s += v; q += v*v;
    }
    ssum[tid] = s; ssq[tid] = q;
    __syncthreads();
    if (tid < 128) {
        part[blockIdx.x*256 + tid]       = ssum[tid] + ssum[tid+128];
        part[blockIdx.x*256 + 128 + tid] = ssq[tid]  + ssq[tid+128];
    }
}

__global__ __launch_bounds__(128) void stats_kernel(const float* __restrict__ part,
                                                    const float* __restrict__ g,
                                                    const float* __restrict__ bias,
                                                    float* __restrict__ scale,
                                                    float* __restrict__ shift) {
    int c = threadIdx.x;
    float s = 0.f, q = 0.f;
    for (int b = 0; b < 256; ++b) {
        s += part[b*256 + c];
        q += part[b*256 + 128 + c];
    }
    float mu  = s / (float)N_;
    float var = q / (float)N_ - mu*mu;
    float inv = rsqrtf(var + EPS_);
    float sc  = inv * g[c];
    scale[c] = sc;
    shift[c] = bias[c] - mu * sc;
}

__global__ __launch_bounds__(256) void bnrelu_kernel(float* __restrict__ x,
                                                     const float* __restrict__ scale,
                                                     const float* __restrict__ shift) {
    int i = blockIdx.x * 256 + threadIdx.x;
    float4 v = ((const float4*)x)[i];
    int c = (i * 4) & 127;
    v.x = fmaxf(0.f, v.x*scale[c]   + shift[c]);
    v.y = fmaxf(0.f, v.y*scale[c+1] + shift[c+1]);
    v.z = fmaxf(0.f, v.z*scale[c+2] + shift[c+2]);
    v.w = fmaxf(0.f, v.w*scale[c+3] + shift[c+3]);
    ((float4*)x)[i] = v;
}

// ---------------------------------------------------------------- 3^3 sparse conv (gather-GEMM, fp32)
#define CSTRIDE 36
__global__ __launch_bounds__(256) void conv3_kernel(const float* __restrict__ h,
                                                    const float* __restrict__ w3,
                                                    const int* __restrict__ table,
                                                    const int* __restrict__ keyb,
                                                    float* __restrict__ h2) {
    __shared__ __align__(16) float At[128 * CSTRIDE];
    __shared__ int jsh[32];
    int tid = threadIdx.x;
    int rowbase = blockIdx.x * 32;
    int rg = tid >> 5, dg = tid & 31;
    float acc[4][4];
#pragma unroll
    for (int i = 0; i < 4; ++i)
#pragma unroll
        for (int k = 0; k < 4; ++k) acc[i][k] = 0.f;

    for (int o = 0; o < 27; ++o) {
        int dx = o/9 - 1, dy = (o/3)%3 - 1, dz = o%3 - 1;
        int okey = dx*4096 + dy*64 + dz;
        __syncthreads();
        if (tid < 32) jsh[tid] = table[keyb[rowbase + tid] + okey];
        __syncthreads();
#pragma unroll
        for (int t = 0; t < 16; ++t) {
            int flat = t*256 + tid;
            int r = flat >> 7, c = flat & 127;
            int j = jsh[r];
            At[c*CSTRIDE + r] = (j >= 0) ? h[j*128 + c] : 0.f;
        }
        __syncthreads();
        const float* w3o = w3 + o*128*128;
#pragma unroll 4
        for (int c = 0; c < 128; ++c) {
            float4 a = *(const float4*)&At[c*CSTRIDE + 4*rg];
            float4 w = *(const float4*)&w3o[c*128 + 4*dg];
            acc[0][0] += a.x*w.x; acc[0][1] += a.x*w.y; acc[0][2] += a.x*w.z; acc[0][3] += a.x*w.w;
            acc[1][0] += a.y*w.x; acc[1][1] += a.y*w.y; acc[1][2] += a.y*w.z; acc[1][3] += a.y*w.w;
            acc[2][0] += a.z*w.x; acc[2][1] += a.z*w.y; acc[2][2] += a.z*w.z; acc[2][3] += a.z*w.w;
            acc[3][0] += a.w*w.x; acc[3][1] += a.w*w.y; acc[3][2] += a.w*w.z; acc[3][3] += a.w*w.w;
        }
    }
#pragma unroll
    for (int i = 0; i < 4; ++i) {
        float4 v = make_float4(acc[i][0], acc[i][1], acc[i][2], acc[i][3]);
        *(float4*)&h2[(rowbase + 4*rg + i)*128 + 4*dg] = v;
    }
}

// ---------------------------------------------------------------- final 1x1 conv
__global__ __launch_bounds__(256) void out_kernel(const float* __restrict__ h2,
                                                  const float* __restrict__ wout,
                                                  float* __restrict__ out) {
    int tid = threadIdx.x;
    int r = tid >> 4, d = tid & 15;
    int row = blockIdx.x * 16 + r;
    float acc = 0.f;
    for (int c = 0; c < 128; ++c)
        acc += h2[row*128 + c] * wout[c*16 + d];
    out[row*16 + d] = acc;
}

// ---------------------------------------------------------------- launch
extern "C" void kernel_launch(void* const* d_in, const int* in_sizes, int n_in,
                              void* d_out, int out_size, void* d_ws, size_t ws_size,
                              hipStream_t stream) {
    const int*   coords = (const int*)d_in[0];
    const float* feats  = (const float*)d_in[1];
    const float* w1     = (const float*)d_in[2];
    const float* g1     = (const float*)d_in[3];
    const float* b1     = (const float*)d_in[4];
    const float* w3     = (const float*)d_in[5];
    const float* g2     = (const float*)d_in[6];
    const float* b2     = (const float*)d_in[7];
    const float* wout   = (const float*)d_in[8];
    float* out = (float*)d_out;

    char* ws = (char*)d_ws;
    int*   table_base = (int*)(ws);                           // (TBL+GUARD) ints ~ 4.03 MB
    int*   table  = table_base + GUARD;
    int*   packed = (int*)(ws + (5u<<20));                    // 128 KB
    int*   keyb   = (int*)(ws + (5u<<20) + (256u<<10));       // 128 KB
    int*   nbr    = (int*)(ws + (5u<<20) + (512u<<10));       // 1 MB
    int*   flagcnt  = (int*)(ws + (5u<<20) + (1536u<<10));    // 4 B
    int*   flaglist = (int*)(ws + (5u<<20) + (1540u<<10));    // 128 KB
    float* h      = (float*)(ws + (7u<<20));                  // 16 MB
    float* h2     = (float*)(ws + (23u<<20));                 // 16 MB
    float* part   = (float*)(ws + (39u<<20));                 // 256 KB
    float* scale1 = (float*)(ws + (39u<<20) + (512u<<10));
    float* shift1 = scale1 + 128;
    float* scale2 = shift1 + 128;
    float* shift2 = scale2 + 128;

    hipMemsetAsync(table_base, 0xFF, (TBL + GUARD) * sizeof(int), stream);
    hipMemsetAsync(flagcnt, 0, sizeof(int), stream);
    prep_kernel      <<<N_/256, 256, 0, stream>>>(coords, table, packed, keyb);
    knn_window_kernel<<<N_/64, 256, 0, stream>>>(table, keyb, nbr, flagcnt, flaglist);
    knn_bf_kernel    <<<256, 256, 0, stream>>>(packed, flagcnt, flaglist, nbr);
    h1_kernel        <<<N_/16, 256, 0, stream>>>(feats, nbr, w1, h);
    reduce_kernel    <<<N_/128, 256, 0, stream>>>(h, part);
    stats_kernel     <<<1, 128, 0, stream>>>(part, g1, b1, scale1, shift1);
    bnrelu_kernel    <<<(N_*H_/4)/256, 256, 0, stream>>>(h, scale1, shift1);
    conv3_kernel     <<<N_/32, 256, 0, stream>>>(h, w3, table, keyb, h2);
    reduce_kernel    <<<N_/128, 256, 0, stream>>>(h2, part);
    stats_kernel     <<<1, 128, 0, stream>>>(part, g2, b2, scale2, shift2);
    bnrelu_kernel    <<<(N_*H_/4)/256, 256, 0, stream>>>(h2, scale2, shift2);
    out_kernel       <<<N_/16, 256, 0, stream>>>(h2, wout, out);
}

// Round 3
// 266.330 us; speedup vs baseline: 4.2498x; 2.4213x over previous
//
#include <hip/hip_runtime.h>
#include <hip/hip_bf16.h>

#define B_   4
#define M_   8192
#define N_   32768
#define H_   128
#define EPS_ 1e-5f
#define TBL  1048576   // 4 * 64^3 dense hash table
#define GUARD 8192     // negative-offset guard for window probes

typedef short short8 __attribute__((ext_vector_type(8)));   // 8 bf16 (4 VGPRs)
typedef float f32x4  __attribute__((ext_vector_type(4)));   // 4 fp32 acc

// ---------------------------------------------------------------- prep
__global__ __launch_bounds__(256) void prep_kernel(const int* __restrict__ coords,
                                                   int* __restrict__ table,
                                                   int* __restrict__ packed,
                                                   int* __restrict__ keyb) {
    int n = blockIdx.x * 256 + threadIdx.x;
    int b = coords[4*n+0], x = coords[4*n+1], y = coords[4*n+2], z = coords[4*n+3];
    packed[n] = (x << 10) | (y << 5) | z;
    int key = ((b*64 + x+1)*64 + y+1)*64 + (z+1);
    keyb[n] = key;
    table[key] = n;
}

// ---------------------------------------------------------------- w3 -> bf16 MFMA B-fragment layout
// w3f[t*8+j], t = (o<<11)|(ks<<9)|(ct<<6)|lane :
//   value = bf16(w3[o][c][n]), c = ks*32 + (lane>>4)*8 + j, n = ct*16 + (lane&15)
__global__ __launch_bounds__(256) void w3pack_kernel(const float* __restrict__ w3,
                                                     ushort* __restrict__ w3f) {
    int t = blockIdx.x * 256 + threadIdx.x;   // 27*2048 = 55296 threads exactly
    int lane = t & 63;
    int ct   = (t >> 6) & 7;
    int ks   = (t >> 9) & 3;
    int o    = t >> 11;
    int quad = lane >> 4, l15 = lane & 15;
    int n = ct*16 + l15;
    const float* src = w3 + o*16384;
    ushort out8[8];
#pragma unroll
    for (int j = 0; j < 8; ++j) {
        int c = ks*32 + quad*8 + j;
        float v = src[c*128 + n];
        __hip_bfloat16 bv = __float2bfloat16(v);
        ushort u; __builtin_memcpy(&u, &bv, 2);
        out8[j] = u;
    }
    *(uint4*)&w3f[t*8] = *(uint4*)out8;
}

// ---------------------------------------------------------------- kNN via radius-2 window
__global__ __launch_bounds__(256) void knn_window_kernel(const int* __restrict__ table,
                                                         const int* __restrict__ keyb,
                                                         int* __restrict__ nbr,
                                                         int* __restrict__ flagcnt,
                                                         int* __restrict__ flaglist) {
    __shared__ int okey_sh[125], d2_sh[125];
    __shared__ int tops[256 * 8];
    int tid = threadIdx.x;
    if (tid < 125) {
        int dx = tid / 25 - 2, rr = tid % 25, dy = rr / 5 - 2, dz = rr % 5 - 2;
        okey_sh[tid] = dx * 4096 + dy * 64 + dz;
        d2_sh[tid]   = dx*dx + dy*dy + dz*dz;
    }
    __syncthreads();

    int q   = blockIdx.x * 64 + (tid >> 2);
    int sub = tid & 3;
    int kb  = keyb[q];

    int top[8];
#pragma unroll
    for (int k = 0; k < 8; ++k) top[k] = 0x7FFFFFFF;

    int base = sub * 32;
    int cnt  = (sub == 3) ? 29 : 32;
    for (int i = 0; i < cnt; ++i) {
        int idx = base + i;
        int j = table[kb + okey_sh[idx]];
        if (j >= 0) {
            int key = (d2_sh[idx] << 13) | (j & 8191);
            if (key < top[7]) {
#pragma unroll
                for (int k = 7; k >= 1; --k)
                    top[k] = (key < top[k]) ? max(key, top[k-1]) : top[k];
                top[0] = min(key, top[0]);
            }
        }
    }
#pragma unroll
    for (int k = 0; k < 8; ++k) tops[tid*8 + k] = top[k];
    __syncthreads();

    if (sub == 0) {
        const int* L = &tops[tid*8];
        int ia0 = 0, ia1 = 0, ia2 = 0, ia3 = 0;
        int res[8];
#pragma unroll
        for (int k = 0; k < 8; ++k) {
            int v0 = L[ia0], v1 = L[8 + ia1], v2 = L[16 + ia2], v3 = L[24 + ia3];
            int m01 = min(v0, v1), m23 = min(v2, v3);
            int m = min(m01, m23);
            res[k] = m;
            if (m == v0) ++ia0; else if (m == v1) ++ia1;
            else if (m == v2) ++ia2; else ++ia3;
        }
        int bb = q & ~(M_-1);
        if ((res[7] >> 13) <= 8) {
#pragma unroll
            for (int k = 0; k < 8; ++k) nbr[q*8 + k] = bb + (res[k] & 8191);
        } else {
            int pos = atomicAdd(flagcnt, 1);
            flaglist[pos] = q;
        }
    }
}

// ---------------------------------------------------------------- brute-force cleanup
__global__ __launch_bounds__(256) void knn_bf_kernel(const int* __restrict__ packed,
                                                     const int* __restrict__ flagcnt,
                                                     const int* __restrict__ flaglist,
                                                     int* __restrict__ nbr) {
    __shared__ int tops[256 * 8];
    int tid = threadIdx.x;
    int cnt = *flagcnt;
    for (int f = blockIdx.x; f < cnt; f += gridDim.x) {
        int n = flaglist[f];
        int bb = n & ~(M_-1);
        int p = packed[n];
        int qx = (p >> 10) & 31, qy = (p >> 5) & 31, qz = p & 31;
        int top[8];
#pragma unroll
        for (int k = 0; k < 8; ++k) top[k] = 0x7FFFFFFF;
        for (int j = tid; j < M_; j += 256) {
            int c = packed[bb + j];
            int dx = qx - ((c >> 10) & 31);
            int dy = qy - ((c >> 5) & 31);
            int dz = qz - (c & 31);
            int d2 = dx*dx + dy*dy + dz*dz;
            int key = (d2 << 13) | j;
            if (key < top[7]) {
#pragma unroll
                for (int k = 7; k >= 1; --k)
                    top[k] = (key < top[k]) ? max(key, top[k-1]) : top[k];
                top[0] = min(key, top[0]);
            }
        }
#pragma unroll
        for (int k = 0; k < 8; ++k) tops[tid*8 + k] = top[k];
        __syncthreads();
        for (int stride = 128; stride >= 1; stride >>= 1) {
            if (tid < stride) {
                int* A  = &tops[tid*8];
                int* Bp = &tops[(tid+stride)*8];
                int r[8]; int ia = 0, ib = 0;
#pragma unroll
                for (int k = 0; k < 8; ++k) {
                    int a = A[ia], b2 = Bp[ib];
                    if (a <= b2) { r[k] = a; ++ia; } else { r[k] = b2; ++ib; }
                }
#pragma unroll
                for (int k = 0; k < 8; ++k) A[k] = r[k];
            }
            __syncthreads();
        }
        if (tid == 0) {
#pragma unroll
            for (int k = 0; k < 8; ++k) nbr[n*8 + k] = bb + (tops[k] & 8191);
        }
        __syncthreads();
    }
}

// ---------------------------------------------------------------- 1x1 conv (combined @ w1)
__global__ __launch_bounds__(256) void h1_kernel(const float* __restrict__ feats,
                                                 const int* __restrict__ nbr,
                                                 const float* __restrict__ w1,
                                                 float* __restrict__ hpre) {
    __shared__ float comb[16][72];
    int tid = threadIdx.x;
    int rowbase = blockIdx.x * 16;
    if (tid < 144) {
        int r = tid / 9, s = tid % 9;
        int grow = rowbase + r;
        int idx = (s == 0) ? grow : nbr[grow*8 + (s-1)];
        const float4* f = (const float4*)(feats + idx * 8);
        float4 a = f[0], b = f[1];
        float* dp = &comb[r][s*8];
        dp[0]=a.x; dp[1]=a.y; dp[2]=a.z; dp[3]=a.w;
        dp[4]=b.x; dp[5]=b.y; dp[6]=b.z; dp[7]=b.w;
    }
    __syncthreads();
    int c = tid & 127, rh = tid >> 7;
    float acc[8];
#pragma unroll
    for (int i = 0; i < 8; ++i) acc[i] = 0.f;
    for (int s = 0; s < 72; ++s) {
        float w = w1[s*128 + c];
#pragma unroll
        for (int i = 0; i < 8; ++i)
            acc[i] += comb[rh*8 + i][s] * w;
    }
#pragma unroll
    for (int i = 0; i < 8; ++i)
        hpre[(rowbase + rh*8 + i)*128 + c] = acc[i];
}

// ---------------------------------------------------------------- BN stats
__global__ __launch_bounds__(256) void reduce_kernel(const float* __restrict__ src,
                                                     float* __restrict__ part) {
    __shared__ float ssum[256], ssq[256];
    int tid = threadIdx.x;
    int c = tid & 127, halfr = tid >> 7;
    int rowbase = blockIdx.x * 128 + halfr * 64;
    float s = 0.f, q = 0.f;
    for (int i = 0; i < 64; ++i) {
        float v = src[(rowbase + i)*128 + c];
        s += v; q += v*v;
    }
    ssum[tid] = s; ssq[tid] = q;
    __syncthreads();
    if (tid < 128) {
        part[blockIdx.x*256 + tid]       = ssum[tid] + ssum[tid+128];
        part[blockIdx.x*256 + 128 + tid] = ssq[tid]  + ssq[tid+128];
    }
}

__global__ __launch_bounds__(128) void stats_kernel(const float* __restrict__ part,
                                                    const float* __restrict__ g,
                                                    const float* __restrict__ bias,
                                                    float* __restrict__ scale,
                                                    float* __restrict__ shift) {
    int c = threadIdx.x;
    float s = 0.f, q = 0.f;
    for (int b = 0; b < 256; ++b) {
        s += part[b*256 + c];
        q += part[b*256 + 128 + c];
    }
    float mu  = s / (float)N_;
    float var = q / (float)N_ - mu*mu;
    float inv = rsqrtf(var + EPS_);
    float sc  = inv * g[c];
    scale[c] = sc;
    shift[c] = bias[c] - mu * sc;
}

// BN+ReLU -> bf16 output (for conv3 A operand)
__global__ __launch_bounds__(256) void bnrelu_bf16_kernel(const float* __restrict__ x,
                                                          const float* __restrict__ scale,
                                                          const float* __restrict__ shift,
                                                          ushort* __restrict__ y) {
    int i = blockIdx.x * 256 + threadIdx.x;
    float4 v = ((const float4*)x)[i];
    int c = (i * 4) & 127;
    v.x = fmaxf(0.f, v.x*scale[c]   + shift[c]);
    v.y = fmaxf(0.f, v.y*scale[c+1] + shift[c+1]);
    v.z = fmaxf(0.f, v.z*scale[c+2] + shift[c+2]);
    v.w = fmaxf(0.f, v.w*scale[c+3] + shift[c+3]);
    ushort o[4];
#pragma unroll
    for (int k = 0; k < 4; ++k) {
        float f = (&v.x)[k];
        __hip_bfloat16 bv = __float2bfloat16(f);
        __builtin_memcpy(&o[k], &bv, 2);
    }
    ((ushort4*)y)[i] = make_ushort4(o[0], o[1], o[2], o[3]);
}

__global__ __launch_bounds__(256) void bnrelu_kernel(float* __restrict__ x,
                                                     const float* __restrict__ scale,
                                                     const float* __restrict__ shift) {
    int i = blockIdx.x * 256 + threadIdx.x;
    float4 v = ((const float4*)x)[i];
    int c = (i * 4) & 127;
    v.x = fmaxf(0.f, v.x*scale[c]   + shift[c]);
    v.y = fmaxf(0.f, v.y*scale[c+1] + shift[c+1]);
    v.z = fmaxf(0.f, v.z*scale[c+2] + shift[c+2]);
    v.w = fmaxf(0.f, v.w*scale[c+3] + shift[c+3]);
    ((float4*)x)[i] = v;
}

// ---------------------------------------------------------------- 3^3 sparse conv: bf16 MFMA gather-GEMM
// block: 64 rows x 128 cols, 4 waves (each 32 rows x 64 cols = 2x4 tiles of 16x16)
// K = 27 offsets x 128 channels, inner step 32 (mfma_f32_16x16x32_bf16)
#define ASTR 136    // 128 + 8 pad: breaks pow2 bank stride, keeps 16B alignment
__global__ __launch_bounds__(256) void conv3_mfma_kernel(const ushort* __restrict__ hb,
                                                         const ushort* __restrict__ w3f,
                                                         const int* __restrict__ table,
                                                         const int* __restrict__ keyb,
                                                         float* __restrict__ h2) {
    __shared__ ushort As[64 * ASTR];    // 17408 B, [row][c]
    __shared__ ushort Bs[16384];        // 32768 B, fragment-major copy of w3f[o]
    __shared__ int jsh[64];
    int tid = threadIdx.x;
    int lane = tid & 63, wid = tid >> 6;
    int quad = lane >> 4, l15 = lane & 15;
    int rowbase = blockIdx.x * 64;
    int rb = (wid >> 1) * 2;        // row-tile base (0 or 2)
    int cb = (wid & 1) * 4;         // col-tile base (0 or 4)

    f32x4 acc[2][4];
#pragma unroll
    for (int i = 0; i < 2; ++i)
#pragma unroll
        for (int c = 0; c < 4; ++c)
            acc[i][c] = (f32x4){0.f, 0.f, 0.f, 0.f};

    for (int o = 0; o < 27; ++o) {
        int dx = o/9 - 1, dy = (o/3)%3 - 1, dz = o%3 - 1;
        int okey = dx*4096 + dy*64 + dz;
        __syncthreads();               // protect As/Bs/jsh from previous iter compute
        if (tid < 64) jsh[tid] = table[keyb[rowbase + tid] + okey];
        __syncthreads();
        // stage gathered A rows (zero-fill invalid)
#pragma unroll
        for (int i = 0; i < 4; ++i) {
            int flat = i*256 + tid;             // 1024 chunks of 16B
            int r = flat >> 4, c16 = flat & 15;
            int j = jsh[r];
            uint4 v = make_uint4(0u, 0u, 0u, 0u);
            if (j >= 0) v = *(const uint4*)&hb[j*128 + c16*8];
            *(uint4*)&As[r*ASTR + c16*8] = v;
        }
        // stage B slice (straight 32 KB copy, already fragment-major)
        const ushort* wsrc = w3f + o*16384;
#pragma unroll
        for (int i = 0; i < 8; ++i) {
            int flat = i*256 + tid;             // 2048 chunks of 16B
            *(uint4*)&Bs[flat*8] = *(const uint4*)&wsrc[flat*8];
        }
        __syncthreads();
#pragma unroll
        for (int ks = 0; ks < 4; ++ks) {
            short8 af[2], bfr[4];
#pragma unroll
            for (int i = 0; i < 2; ++i)
                af[i] = *(const short8*)&As[((rb+i)*16 + l15)*ASTR + ks*32 + quad*8];
#pragma unroll
            for (int c = 0; c < 4; ++c)
                bfr[c] = *(const short8*)&Bs[((ks*8 + cb + c)*64 + lane)*8];
#pragma unroll
            for (int i = 0; i < 2; ++i)
#pragma unroll
                for (int c = 0; c < 4; ++c)
                    acc[i][c] = __builtin_amdgcn_mfma_f32_16x16x32_bf16(af[i], bfr[c], acc[i][c], 0, 0, 0);
        }
    }
    // epilogue: D[row = quad*4+reg][col = l15] per 16x16 tile
#pragma unroll
    for (int i = 0; i < 2; ++i)
#pragma unroll
        for (int c = 0; c < 4; ++c)
#pragma unroll
            for (int r = 0; r < 4; ++r) {
                int row = rowbase + (rb+i)*16 + quad*4 + r;
                int col = (cb+c)*16 + l15;
                h2[row*128 + col] = acc[i][c][r];
            }
}

// ---------------------------------------------------------------- final 1x1 conv
__global__ __launch_bounds__(256) void out_kernel(const float* __restrict__ h2,
                                                  const float* __restrict__ wout,
                                                  float* __restrict__ out) {
    int tid = threadIdx.x;
    int r = tid >> 4, d = tid & 15;
    int row = blockIdx.x * 16 + r;
    float acc = 0.f;
    for (int c = 0; c < 128; ++c)
        acc += h2[row*128 + c] * wout[c*16 + d];
    out[row*16 + d] = acc;
}

// ---------------------------------------------------------------- launch
extern "C" void kernel_launch(void* const* d_in, const int* in_sizes, int n_in,
                              void* d_out, int out_size, void* d_ws, size_t ws_size,
                              hipStream_t stream) {
    const int*   coords = (const int*)d_in[0];
    const float* feats  = (const float*)d_in[1];
    const float* w1     = (const float*)d_in[2];
    const float* g1     = (const float*)d_in[3];
    const float* b1     = (const float*)d_in[4];
    const float* w3     = (const float*)d_in[5];
    const float* g2     = (const float*)d_in[6];
    const float* b2     = (const float*)d_in[7];
    const float* wout   = (const float*)d_in[8];
    float* out = (float*)d_out;

    char* ws = (char*)d_ws;
    int*    table_base = (int*)(ws);                              // 4.03 MB
    int*    table   = table_base + GUARD;
    int*    packed  = (int*)(ws + (4352u<<10));                   // 128 KB
    int*    keyb    = (int*)(ws + (4608u<<10));                   // 128 KB
    int*    nbr     = (int*)(ws + (4864u<<10));                   // 1 MB
    int*    flagcnt = (int*)(ws + (5888u<<10));                   // 4 B
    int*    flaglist= (int*)(ws + (5892u<<10));                   // 128 KB
    float*  part    = (float*)(ws + (6144u<<10));                 // 256 KB
    float*  scale1  = (float*)(ws + (6400u<<10));
    float*  shift1  = scale1 + 128;
    float*  scale2  = shift1 + 128;
    float*  shift2  = scale2 + 128;
    ushort* w3f     = (ushort*)(ws + (6656u<<10));                // 0.88 MB
    ushort* hb      = (ushort*)(ws + (7680u<<10));                // 8 MB
    float*  h       = (float*)(ws + (15872u<<10));                // 16 MB
    float*  h2      = h;   // aliased: h is dead once hb is written, conv3 reads only hb

    hipMemsetAsync(table_base, 0xFF, (TBL + GUARD) * sizeof(int), stream);
    hipMemsetAsync(flagcnt, 0, sizeof(int), stream);
    prep_kernel      <<<N_/256, 256, 0, stream>>>(coords, table, packed, keyb);
    w3pack_kernel    <<<216, 256, 0, stream>>>(w3, w3f);
    knn_window_kernel<<<N_/64, 256, 0, stream>>>(table, keyb, nbr, flagcnt, flaglist);
    knn_bf_kernel    <<<256, 256, 0, stream>>>(packed, flagcnt, flaglist, nbr);
    h1_kernel        <<<N_/16, 256, 0, stream>>>(feats, nbr, w1, h);
    reduce_kernel    <<<N_/128, 256, 0, stream>>>(h, part);
    stats_kernel     <<<1, 128, 0, stream>>>(part, g1, b1, scale1, shift1);
    bnrelu_bf16_kernel<<<(N_*H_/4)/256, 256, 0, stream>>>(h, scale1, shift1, hb);
    conv3_mfma_kernel<<<N_/64, 256, 0, stream>>>(hb, w3f, table, keyb, h2);
    reduce_kernel    <<<N_/128, 256, 0, stream>>>(h2, part);
    stats_kernel     <<<1, 128, 0, stream>>>(part, g2, b2, scale2, shift2);
    bnrelu_kernel    <<<(N_*H_/4)/256, 256, 0, stream>>>(h2, scale2, shift2);
    out_kernel       <<<N_/16, 256, 0, stream>>>(h2, wout, out);
}